// Round 1
// baseline (2404.662 us; speedup 1.0000x reference)
//
#include <hip/hip_runtime.h>

// Problem constants (Summarizer GConvGRU)
#define BB 8
#define TT 20
#define NV 10000
#define FF 9
#define EE 160000
#define HDIM 64
#define BTT (BB*TT)      // 160
#define NROWS (BB*NV)    // 80000
#define NNZ (EE+NV)      // 170000

static __device__ __forceinline__ float fsig(float x){
  float e = __expf(-x);
  return __fdividef(1.0f, 1.0f + e);
}
static __device__ __forceinline__ float ftanh(float x){
  // tanh(x) = 1 - 2e/(1+e), e = exp(-2x); safe for |x| << 44
  float e = __expf(-2.0f*x);
  float r = __fdividef(1.0f, 1.0f + e);
  return fmaf(-2.0f*e, r, 1.0f);
}

// ---------------- preprocessing kernels ----------------

__global__ void k_init_count(int* count){
  int n = blockIdx.x*256 + threadIdx.x;
  if (n < NV) count[n] = 1;               // self-loop
}

__global__ void k_count(const int* __restrict__ ei, int* count){
  int e = blockIdx.x*256 + threadIdx.x;
  if (e < EE) atomicAdd(&count[ei[EE + e]], 1);   // dst row
}

__global__ void k_scan(const int* __restrict__ count, int* __restrict__ row_ptr,
                       int* __restrict__ cursor){
  __shared__ int part[1024];
  int tid = threadIdx.x;
  int beg = tid*10;
  int s = 0;
  for (int i=0;i<10;i++){ int idx=beg+i; if (idx<NV) s += count[idx]; }
  part[tid]=s; __syncthreads();
  for (int off=1; off<1024; off<<=1){
    int v = (tid>=off) ? part[tid-off] : 0;
    __syncthreads();
    part[tid] += v;
    __syncthreads();
  }
  int run = (tid>0) ? part[tid-1] : 0;
  for (int i=0;i<10;i++){
    int idx=beg+i;
    if (idx<NV){ row_ptr[idx]=run; cursor[idx]=run+1; run += count[idx]; }
  }
  if (tid==1023) row_ptr[NV] = part[1023];
}

__global__ void k_dinv(const int* __restrict__ count, float* __restrict__ dinv){
  int n = blockIdx.x*256 + threadIdx.x;
  if (n < NV) dinv[n] = rsqrtf((float)count[n]);   // count >= 1 always
}

__global__ void k_self(const int* __restrict__ row_ptr, const float* __restrict__ dinv,
                       int* __restrict__ csr_src, float* __restrict__ csr_w){
  int n = blockIdx.x*256 + threadIdx.x;
  if (n < NV){
    int p = row_ptr[n];
    csr_src[p] = n;
    csr_w[p] = dinv[n]*dinv[n];
  }
}

__global__ void k_scatter(const int* __restrict__ ei, const float* __restrict__ dinv,
                          int* cursor, int* __restrict__ csr_src, float* __restrict__ csr_w){
  int e = blockIdx.x*256 + threadIdx.x;
  if (e < EE){
    int s = ei[e];
    int d = ei[EE + e];
    int p = atomicAdd(&cursor[d], 1);
    csr_src[p] = s;
    csr_w[p] = dinv[s]*dinv[d];
  }
}

// u_g = Wc_g @ Wl_g[:64], c_g = bc_g @ Wl_g[:64] + bl_g   (uc layout: g*128 + {0:u, 64:c})
__global__ void k_uc(const float* Wcz,const float* bcz,const float* Wlz,const float* blz,
                     const float* Wcr,const float* bcr,const float* Wlr,const float* blr,
                     const float* Wch,const float* bch,const float* Wlh,const float* blh,
                     float* uc){
  int tid = threadIdx.x;           // 192
  int g = tid>>6, h = tid&63;
  const float* Wc = (g==0)?Wcz:(g==1)?Wcr:Wch;
  const float* bc = (g==0)?bcz:(g==1)?bcr:bch;
  const float* Wl = (g==0)?Wlz:(g==1)?Wlr:Wlh;
  const float* bl = (g==0)?blz:(g==1)?blr:blh;
  float u=0.f, c=0.f;
  for (int k=0;k<64;++k){
    float wl = Wl[k*64 + h];
    u = fmaf(Wc[k], wl, u);
    c = fmaf(bc[k], wl, c);
  }
  uc[g*128 + h]      = u;
  uc[g*128 + 64 + h] = c + bl[h];
}

// copy obs[...,0:8] -> out[...,0:8]; extract x_rec transposed: xrT[n][bt]
__global__ void k_extract(const float* __restrict__ obs, float* __restrict__ out,
                          float* __restrict__ xrT){
  int i = blockIdx.x*256 + threadIdx.x;
  if (i >= BTT*NV) return;
  const float* orow = obs + (size_t)i*FF;
  float4 a, b4;
  a.x=orow[0]; a.y=orow[1]; a.z=orow[2]; a.w=orow[3];
  b4.x=orow[4]; b4.y=orow[5]; b4.z=orow[6]; b4.w=orow[7];
  float xr = orow[8];
  float* op = out + (size_t)i*72;
  *(float4*)op       = a;
  *(float4*)(op + 4) = b4;
  int bt = i / NV;
  int n  = i - bt*NV;
  xrT[(size_t)n*BTT + bt] = xr;
}

// S[bt][n] = sum over incoming edges (incl self loop) of w * xrT[src][bt]
__global__ void k_spmv(const float* __restrict__ xrT, const int* __restrict__ row_ptr,
                       const int* __restrict__ csr_src, const float* __restrict__ csr_w,
                       float* __restrict__ S){
  int n = blockIdx.x;
  int lane = threadIdx.x;          // 64
  int e0 = row_ptr[n], e1 = row_ptr[n+1];
  float a0=0.f, a1=0.f, a2=0.f;
  for (int e=e0; e<e1; ++e){
    int s = csr_src[e];
    float w = csr_w[e];
    const float* xr = xrT + (size_t)s*BTT;
    a0 = fmaf(w, xr[lane],      a0);
    a1 = fmaf(w, xr[64 + lane], a1);
    if (lane < 32) a2 = fmaf(w, xr[128 + lane], a2);
  }
  S[(size_t)lane*NV + n]        = a0;
  S[(size_t)(64+lane)*NV + n]   = a1;
  if (lane < 32) S[(size_t)(128+lane)*NV + n] = a2;
}

// ---------------- GRU recurrence ----------------
// row-per-lane; H in LDS (stride 66 to break bank stride); weights uniform -> s_load.

static __device__ __forceinline__ void matvec(float (&acc)[64],
                                              const float* hrow,
                                              const float* __restrict__ V){
  #pragma unroll 1
  for (int kb=0; kb<8; ++kb){
    const float* vp = V + kb*512;
    float hk[8];
    #pragma unroll
    for (int i=0;i<8;++i) hk[i] = hrow[kb*8 + i];
    #pragma unroll
    for (int h=0; h<64; ++h){
      float a = acc[h];
      #pragma unroll
      for (int i=0;i<8;++i) a = fmaf(hk[i], vp[i*64 + h], a);
      acc[h] = a;
    }
  }
}

__global__ __launch_bounds__(128, 2) void k_gru(
    const float* __restrict__ S, const float* __restrict__ Wlz,
    const float* __restrict__ Wlr, const float* __restrict__ Wlh,
    const float* __restrict__ uc, float* __restrict__ out)
{
  __shared__ float hbuf[128*66];
  const int tid = threadIdx.x;
  int rho = blockIdx.x*128 + tid;          // 625*128 == 80000 exactly
  const int b = rho / NV;
  const int n = rho - b*NV;
  const float* Vz = Wlz + 64*64;
  const float* Vr = Wlr + 64*64;
  const float* Vh = Wlh + 64*64;
  float* hrow = &hbuf[tid*66];
  #pragma unroll
  for (int h=0; h<64; ++h) hrow[h] = 0.0f;

  float zreg[64], hs[64], acc[64];
  const float* Sp = S + n;
  float* op0 = out + ((size_t)(b*TT)*NV + n)*72 + 8;

  #pragma unroll 1
  for (int t=0; t<TT; ++t){
    float s = Sp[(size_t)(b*TT + t)*NV];

    // ---- z path: acc = s*u_z + c_z + H @ Vz ; z = sigmoid(acc)
    #pragma unroll
    for (int h=0;h<64;++h) acc[h] = fmaf(uc[h], s, uc[64+h]);
    matvec(acc, hrow, Vz);
    #pragma unroll
    for (int h=0;h<64;++h) zreg[h] = fsig(acc[h]);

    // ---- r path: acc = s*u_r + c_r + H @ Vr ; overwrite LDS H with H*r, save H
    #pragma unroll
    for (int h=0;h<64;++h) acc[h] = fmaf(uc[128+h], s, uc[192+h]);
    matvec(acc, hrow, Vr);
    #pragma unroll
    for (int h=0;h<64;++h){
      float hv = hrow[h];
      hs[h] = hv;
      hrow[h] = hv * fsig(acc[h]);
    }

    // ---- h path: acc = s*u_h + c_h + (H*r) @ Vh
    #pragma unroll
    for (int h=0;h<64;++h) acc[h] = fmaf(uc[256+h], s, uc[320+h]);
    matvec(acc, hrow, Vh);

    // ---- update + store
    float* op = op0 + (size_t)t*NV*72;
    #pragma unroll
    for (int q=0; q<16; ++q){
      float v[4];
      #pragma unroll
      for (int j=0;j<4;++j){
        int h = q*4 + j;
        float htil = ftanh(acc[h]);
        float hn = fmaf(zreg[h], hs[h] - htil, htil);  // z*H + (1-z)*htil
        hrow[h] = hn;
        v[j] = hn;
      }
      float4 f4; f4.x=v[0]; f4.y=v[1]; f4.z=v[2]; f4.w=v[3];
      *(float4*)(op + q*4) = f4;
    }
  }
}

// ---------------- launcher ----------------

extern "C" void kernel_launch(void* const* d_in, const int* in_sizes, int n_in,
                              void* d_out, int out_size, void* d_ws, size_t ws_size,
                              hipStream_t stream) {
  const float* obs  = (const float*)d_in[0];
  const int*   ei   = (const int*)d_in[1];
  const float* Wcz = (const float*)d_in[2];  const float* bcz = (const float*)d_in[3];
  const float* Wlz = (const float*)d_in[4];  const float* blz = (const float*)d_in[5];
  const float* Wcr = (const float*)d_in[6];  const float* bcr = (const float*)d_in[7];
  const float* Wlr = (const float*)d_in[8];  const float* blr = (const float*)d_in[9];
  const float* Wch = (const float*)d_in[10]; const float* bch = (const float*)d_in[11];
  const float* Wlh = (const float*)d_in[12]; const float* blh = (const float*)d_in[13];
  float* out = (float*)d_out;

  char* w = (char*)d_ws;
  size_t off = 0;
  auto alloc = [&](size_t bytes) -> void* {
    void* p = w + off;
    off = (off + bytes + 255) & ~(size_t)255;
    return p;
  };
  float* xrT     = (float*)alloc((size_t)NV*BTT*4);   // 6.4 MB
  float* S       = (float*)alloc((size_t)BTT*NV*4);   // 6.4 MB
  int*   count   = (int*)  alloc((size_t)NV*4);
  int*   row_ptr = (int*)  alloc((size_t)(NV+1)*4);
  int*   cursor  = (int*)  alloc((size_t)NV*4);
  float* dinv    = (float*)alloc((size_t)NV*4);
  int*   csr_src = (int*)  alloc((size_t)NNZ*4);
  float* csr_w   = (float*)alloc((size_t)NNZ*4);
  float* uc      = (float*)alloc(384*4);

  hipLaunchKernelGGL(k_init_count, dim3((NV+255)/256), dim3(256), 0, stream, count);
  hipLaunchKernelGGL(k_count,      dim3((EE+255)/256), dim3(256), 0, stream, ei, count);
  hipLaunchKernelGGL(k_scan,       dim3(1), dim3(1024), 0, stream, count, row_ptr, cursor);
  hipLaunchKernelGGL(k_dinv,       dim3((NV+255)/256), dim3(256), 0, stream, count, dinv);
  hipLaunchKernelGGL(k_self,       dim3((NV+255)/256), dim3(256), 0, stream, row_ptr, dinv, csr_src, csr_w);
  hipLaunchKernelGGL(k_scatter,    dim3((EE+255)/256), dim3(256), 0, stream, ei, dinv, cursor, csr_src, csr_w);
  hipLaunchKernelGGL(k_uc,         dim3(1), dim3(192), 0, stream,
                     Wcz,bcz,Wlz,blz, Wcr,bcr,Wlr,blr, Wch,bch,Wlh,blh, uc);
  hipLaunchKernelGGL(k_extract,    dim3((BTT*NV+255)/256), dim3(256), 0, stream, obs, out, xrT);
  hipLaunchKernelGGL(k_spmv,       dim3(NV), dim3(64), 0, stream, xrT, row_ptr, csr_src, csr_w, S);
  hipLaunchKernelGGL(k_gru,        dim3(NROWS/128), dim3(128), 0, stream, S, Wlz, Wlr, Wlh, uc, out);
}

// Round 5
// 1750.139 us; speedup vs baseline: 1.3740x; 1.3740x over previous
//
#include <hip/hip_runtime.h>

// Problem constants (Summarizer GConvGRU)
#define BB 8
#define TT 20
#define NV 10000
#define FF 9
#define EE 160000
#define BTT (BB*TT)      // 160
#define NROWS (BB*NV)    // 80000
#define NNZ (EE+NV)      // 170000
#define RPW 40           // rows per wave (40 | 10000, gives 2000 waves = ~2/SIMD)
#define NWAVES (NROWS/RPW)   // 2000
#define WPB 4                // waves per block (256 threads)
#define NBLK (NWAVES/WPB)    // 500

static __device__ __forceinline__ float fsig(float x){
  float e = __expf(-x);
  return __fdividef(1.0f, 1.0f + e);
}
static __device__ __forceinline__ float ftanh(float x){
  float e = __expf(-2.0f*x);
  float r = __fdividef(1.0f, 1.0f + e);
  return fmaf(-2.0f*e, r, 1.0f);
}
// broadcast lane k of v to all lanes (SGPR result)
static __device__ __forceinline__ float rlane(float v, int k){
  return __int_as_float(__builtin_amdgcn_readlane(__float_as_int(v), k));
}

// ---------------- preprocessing kernels ----------------

__global__ void k_init_count(int* count){
  int n = blockIdx.x*256 + threadIdx.x;
  if (n < NV) count[n] = 1;               // self-loop
}

__global__ void k_count(const int* __restrict__ ei, int* count){
  int e = blockIdx.x*256 + threadIdx.x;
  if (e < EE) atomicAdd(&count[ei[EE + e]], 1);   // dst row
}

__global__ void k_scan(const int* __restrict__ count, int* __restrict__ row_ptr,
                       int* __restrict__ cursor){
  __shared__ int part[1024];
  int tid = threadIdx.x;
  int beg = tid*10;
  int s = 0;
  for (int i=0;i<10;i++){ int idx=beg+i; if (idx<NV) s += count[idx]; }
  part[tid]=s; __syncthreads();
  for (int off=1; off<1024; off<<=1){
    int v = (tid>=off) ? part[tid-off] : 0;
    __syncthreads();
    part[tid] += v;
    __syncthreads();
  }
  int run = (tid>0) ? part[tid-1] : 0;
  for (int i=0;i<10;i++){
    int idx=beg+i;
    if (idx<NV){ row_ptr[idx]=run; cursor[idx]=run+1; run += count[idx]; }
  }
  if (tid==1023) row_ptr[NV] = part[1023];
}

__global__ void k_dinv(const int* __restrict__ count, float* __restrict__ dinv){
  int n = blockIdx.x*256 + threadIdx.x;
  if (n < NV) dinv[n] = rsqrtf((float)count[n]);
}

__global__ void k_self(const int* __restrict__ row_ptr, const float* __restrict__ dinv,
                       int* __restrict__ csr_src, float* __restrict__ csr_w){
  int n = blockIdx.x*256 + threadIdx.x;
  if (n < NV){
    int p = row_ptr[n];
    csr_src[p] = n;
    csr_w[p] = dinv[n]*dinv[n];
  }
}

__global__ void k_scatter(const int* __restrict__ ei, const float* __restrict__ dinv,
                          int* cursor, int* __restrict__ csr_src, float* __restrict__ csr_w){
  int e = blockIdx.x*256 + threadIdx.x;
  if (e < EE){
    int s = ei[e];
    int d = ei[EE + e];
    int p = atomicAdd(&cursor[d], 1);
    csr_src[p] = s;
    csr_w[p] = dinv[s]*dinv[d];
  }
}

// u_g = Wc_g @ Wl_g[:64], c_g = bc_g @ Wl_g[:64] + bl_g   (uc layout: g*128 + {0:u, 64:c})
__global__ void k_uc(const float* Wcz,const float* bcz,const float* Wlz,const float* blz,
                     const float* Wcr,const float* bcr,const float* Wlr,const float* blr,
                     const float* Wch,const float* bch,const float* Wlh,const float* blh,
                     float* uc){
  int tid = threadIdx.x;           // 192
  int g = tid>>6, h = tid&63;
  const float* Wc = (g==0)?Wcz:(g==1)?Wcr:Wch;
  const float* bc = (g==0)?bcz:(g==1)?bcr:bch;
  const float* Wl = (g==0)?Wlz:(g==1)?Wlr:Wlh;
  const float* bl = (g==0)?blz:(g==1)?blr:blh;
  float u=0.f, c=0.f;
  for (int k=0;k<64;++k){
    float wl = Wl[k*64 + h];
    u = fmaf(Wc[k], wl, u);
    c = fmaf(bc[k], wl, c);
  }
  uc[g*128 + h]      = u;
  uc[g*128 + 64 + h] = c + bl[h];
}

// extract x_rec transposed: xrT[n][bt]  (out[...,0:8] written by k_gru)
__global__ void k_extract(const float* __restrict__ obs, float* __restrict__ xrT){
  int i = blockIdx.x*256 + threadIdx.x;
  if (i >= BTT*NV) return;
  float xr = obs[(size_t)i*FF + 8];
  int bt = i / NV;
  int n  = i - bt*NV;
  xrT[(size_t)n*BTT + bt] = xr;
}

// S[bt][n] = sum over incoming edges (incl self loop) of w * xrT[src][bt]
__global__ void k_spmv(const float* __restrict__ xrT, const int* __restrict__ row_ptr,
                       const int* __restrict__ csr_src, const float* __restrict__ csr_w,
                       float* __restrict__ S){
  int n = blockIdx.x;
  int lane = threadIdx.x;          // 64
  int e0 = row_ptr[n], e1 = row_ptr[n+1];
  float a0=0.f, a1=0.f, a2=0.f;
  for (int e=e0; e<e1; ++e){
    int s = csr_src[e];
    float w = csr_w[e];
    const float* xr = xrT + (size_t)s*BTT;
    a0 = fmaf(w, xr[lane],      a0);
    a1 = fmaf(w, xr[64 + lane], a1);
    if (lane < 32) a2 = fmaf(w, xr[128 + lane], a2);
  }
  S[(size_t)lane*NV + n]        = a0;
  S[(size_t)(64+lane)*NV + n]   = a1;
  if (lane < 32) S[(size_t)(128+lane)*NV + n] = a2;
}

// ---------------- GRU recurrence ----------------
// lane = output column h; wave = 40 rows x all 20 timesteps.
// V weights register-resident per lane (192 VGPR); H in LDS (1 read + 1 write
// per row); row-uniform H values broadcast to FMAs via v_readlane -> SGPR.

__global__ __launch_bounds__(256, 2) void k_gru(
    const float* __restrict__ S, const float* __restrict__ obs,
    const float* __restrict__ Wlz, const float* __restrict__ Wlr,
    const float* __restrict__ Wlh, const float* __restrict__ uc,
    float* __restrict__ out)
{
  __shared__ float Hs[WPB][RPW*64];    // 40 KB/block, wave-private regions
  const int tid  = threadIdx.x;
  const int w    = tid >> 6;
  const int lane = tid & 63;
  const int W    = blockIdx.x*WPB + w;       // [0, 2000)
  const int row0 = W * RPW;
  const int b    = row0 / NV;                // 40 | 10000 -> whole wave in one b
  const int n0   = row0 - b*NV;

  // V[k][lane] per gate, resident in VGPRs (loaded once, coalesced per k)
  float vz[64], vr[64], vh[64];
  #pragma unroll
  for (int k=0;k<64;++k){
    vz[k] = Wlz[(64+k)*64 + lane];
    vr[k] = Wlr[(64+k)*64 + lane];
    vh[k] = Wlh[(64+k)*64 + lane];
  }
  const float uz = uc[lane],     cz = uc[64+lane];
  const float ur = uc[128+lane], cr = uc[192+lane];
  const float uh = uc[256+lane], ch = uc[320+lane];

  float* hbase = &Hs[w][0];
  #pragma unroll 4
  for (int m=0;m<RPW;++m) hbase[m*64+lane] = 0.0f;

  // S for this wave's rows: lane<40 holds s of row 'lane' (broadcast by readlane)
  float sv = (lane < RPW) ? S[(size_t)(b*TT)*NV + n0 + lane] : 0.0f;

  for (int t=0; t<TT; ++t){
    float sv_next = 0.0f;
    if (t+1 < TT && lane < RPW)
      sv_next = S[(size_t)(b*TT + t + 1)*NV + n0 + lane];
    const float* obsrow = obs + ((size_t)(b*TT+t)*NV + n0)*FF;
    float*       outrow = out + ((size_t)(b*TT+t)*NV + n0)*72;

    for (int m=0; m<RPW; ++m){           // dynamic m: readlane takes SGPR index
      float s = rlane(sv, m);
      float xo = 0.0f;
      if (lane < 8) xo = obsrow[(size_t)m*FF + lane];   // x_other passthrough
      float hvec = hbase[m*64 + lane];   // lane k holds H[m][k]

      // z,r pre-activations: acc = s*u + c + sum_k H[m][k]*V[k][lane]
      float az0 = fmaf(s, uz, cz), az1 = 0.0f;
      float ar0 = fmaf(s, ur, cr), ar1 = 0.0f;
      #pragma unroll
      for (int k=0;k<64;k+=2){
        float h0 = rlane(hvec, k);
        float h1 = rlane(hvec, k+1);
        az0 = fmaf(h0, vz[k],   az0);
        az1 = fmaf(h1, vz[k+1], az1);
        ar0 = fmaf(h0, vr[k],   ar0);
        ar1 = fmaf(h1, vr[k+1], ar1);
      }
      float z = fsig(az0 + az1);
      float r = fsig(ar0 + ar1);
      float hr = hvec * r;               // lane-local (H*r)[lane] — no LDS trip

      float ah0 = fmaf(s, uh, ch), ah1 = 0.0f;
      #pragma unroll
      for (int k=0;k<64;k+=2){
        float g0 = rlane(hr, k);
        float g1 = rlane(hr, k+1);
        ah0 = fmaf(g0, vh[k],   ah0);
        ah1 = fmaf(g1, vh[k+1], ah1);
      }
      float htil = ftanh(ah0 + ah1);
      float hn = fmaf(z, hvec - htil, htil);   // z*H + (1-z)*htil

      hbase[m*64 + lane] = hn;
      outrow[(size_t)m*72 + 8 + lane] = hn;    // cols 8..71
      if (lane < 8) outrow[(size_t)m*72 + lane] = xo;  // cols 0..7 -> full row, no RFO
    }
    sv = sv_next;
  }
}

// ---------------- launcher ----------------

extern "C" void kernel_launch(void* const* d_in, const int* in_sizes, int n_in,
                              void* d_out, int out_size, void* d_ws, size_t ws_size,
                              hipStream_t stream) {
  const float* obs  = (const float*)d_in[0];
  const int*   ei   = (const int*)d_in[1];
  const float* Wcz = (const float*)d_in[2];  const float* bcz = (const float*)d_in[3];
  const float* Wlz = (const float*)d_in[4];  const float* blz = (const float*)d_in[5];
  const float* Wcr = (const float*)d_in[6];  const float* bcr = (const float*)d_in[7];
  const float* Wlr = (const float*)d_in[8];  const float* blr = (const float*)d_in[9];
  const float* Wch = (const float*)d_in[10]; const float* bch = (const float*)d_in[11];
  const float* Wlh = (const float*)d_in[12]; const float* blh = (const float*)d_in[13];
  float* out = (float*)d_out;

  char* w = (char*)d_ws;
  size_t off = 0;
  auto alloc = [&](size_t bytes) -> void* {
    void* p = w + off;
    off = (off + bytes + 255) & ~(size_t)255;
    return p;
  };
  float* xrT     = (float*)alloc((size_t)NV*BTT*4);
  float* S       = (float*)alloc((size_t)BTT*NV*4);
  int*   count   = (int*)  alloc((size_t)NV*4);
  int*   row_ptr = (int*)  alloc((size_t)(NV+1)*4);
  int*   cursor  = (int*)  alloc((size_t)NV*4);
  float* dinv    = (float*)alloc((size_t)NV*4);
  int*   csr_src = (int*)  alloc((size_t)NNZ*4);
  float* csr_w   = (float*)alloc((size_t)NNZ*4);
  float* uc      = (float*)alloc(384*4);

  hipLaunchKernelGGL(k_init_count, dim3((NV+255)/256), dim3(256), 0, stream, count);
  hipLaunchKernelGGL(k_count,      dim3((EE+255)/256), dim3(256), 0, stream, ei, count);
  hipLaunchKernelGGL(k_scan,       dim3(1), dim3(1024), 0, stream, count, row_ptr, cursor);
  hipLaunchKernelGGL(k_dinv,       dim3((NV+255)/256), dim3(256), 0, stream, count, dinv);
  hipLaunchKernelGGL(k_self,       dim3((NV+255)/256), dim3(256), 0, stream, row_ptr, dinv, csr_src, csr_w);
  hipLaunchKernelGGL(k_scatter,    dim3((EE+255)/256), dim3(256), 0, stream, ei, dinv, cursor, csr_src, csr_w);
  hipLaunchKernelGGL(k_uc,         dim3(1), dim3(192), 0, stream,
                     Wcz,bcz,Wlz,blz, Wcr,bcr,Wlr,blr, Wch,bch,Wlh,blh, uc);
  hipLaunchKernelGGL(k_extract,    dim3((BTT*NV+255)/256), dim3(256), 0, stream, obs, xrT);
  hipLaunchKernelGGL(k_spmv,       dim3(NV), dim3(64), 0, stream, xrT, row_ptr, csr_src, csr_w, S);
  hipLaunchKernelGGL(k_gru,        dim3(NBLK), dim3(256), 0, stream, S, obs, Wlz, Wlr, Wlh, uc, out);
}